// Round 14
// baseline (441.832 us; speedup 1.0000x reference)
//
#include <hip/hip_runtime.h>
#include <hip/hip_bf16.h>

typedef _Float16 f16;
typedef _Float16 f16x4 __attribute__((ext_vector_type(4)));
typedef _Float16 f16x8 __attribute__((ext_vector_type(8)));
typedef float    f32x4 __attribute__((ext_vector_type(4)));

static __device__ __forceinline__ float bf2f(__hip_bfloat16 x) { return __bfloat162float(x); }
// dual-dtype float load/store: f32flag=1 -> float*, else bf16*
static __device__ __forceinline__ float ldf(const void* p, long i, int f32flag) {
    return f32flag ? ((const float*)p)[i] : bf2f(((const __hip_bfloat16*)p)[i]);
}
static __device__ __forceinline__ void stf(void* p, long i, int f32flag, float v) {
    if (f32flag) ((float*)p)[i] = v;
    else ((__hip_bfloat16*)p)[i] = __float2bfloat16(v);
}
// async global->LDS, 16B per lane; LDS dest is wave-uniform base + lane*16
static __device__ __forceinline__ void gl2lds16(const f16* g, f16* l) {
    __builtin_amdgcn_global_load_lds(
        (const __attribute__((address_space(1))) unsigned int*)(const void*)g,
        (__attribute__((address_space(3))) unsigned int*)(void*)l, 16, 0, 0);
}

// ---------------- workspace layout (bytes) ----------------
#define OFF_LOGITS 0L                               // S/logits: 32000 x 1024 f16
#define SZ_LOGITS  (32000L * 1024 * 2)
#define OFF_FEAT   (OFF_LOGITS + SZ_LOGITS)         // feat: 32000 x 768 f16
#define SZ_FEAT    (32000L * 768 * 2)
#define OFF_ATTF   (OFF_FEAT + SZ_FEAT)             // att_feat: 32000 x 768 f16
#define SZ_ATTF    (32000L * 768 * 2)
#define OFF_AWT    (OFF_ATTF + SZ_ATTF)             // attn_w^T: 1024 x 768 f16 (rows>=999 zero)
#define SZ_AWT     (1024L * 768 * 2)
#define OFF_WCT    (OFF_AWT + SZ_AWT)               // Wc^T: 128 x 1536 f16 (rows>=75 zero)
#define SZ_WCT     (128L * 1536 * 2)
#define OFF_BIAS   (OFF_WCT + SZ_WCT)               // f32[128]
#define OFF_AB     (OFF_BIAS + 512)                 // attn_b as f32[1024]
#define OFF_FLAG   (OFF_AB + 4096)                  // int flags[2]
#define OFF_FEATT  (OFF_FLAG + 64)                  // feat^T per batch: 32 x 768 x 1024 f16
#define SZ_FEATT   (32L * 768 * 1024 * 2)
#define NEED_A     (OFF_FEATT + SZ_FEATT)           // ~216 MB

// ---------------- front: inline dtype detection + build_feat + awT + weight packing ----------------
// grid 2048: [0,512) feat gather; [512,1280) awT transpose; [1280,2048) wc/bias/abf32
__global__ __launch_bounds__(256) void front_kernel(
    const void* __restrict__ fv, const int* __restrict__ x_idx,
    const void* __restrict__ maskp, int mwords, int* __restrict__ flags,
    int xstride, int mstride, f16* __restrict__ feat,
    const void* __restrict__ attn_w,
    const void* __restrict__ cls_w, const void* __restrict__ cls_b,
    const void* __restrict__ reg_w, const void* __restrict__ reg_b,
    const void* __restrict__ attn_b,
    f16* __restrict__ awT, f16* __restrict__ wcT,
    float* __restrict__ biasc, float* __restrict__ abf32)
{
    int bid = blockIdx.x;
    int t = threadIdx.x;
    // ---- inline detection (uniform across block) ----
    __shared__ int s_cnt, s_bits;
    if (t == 0) { s_cnt = 0; s_bits = 0; }
    __syncthreads();
    {
        const unsigned int* fvu = (const unsigned int*)fv;
        const unsigned int* mu  = (const unsigned int*)maskp;
        int c = 0;
        for (int k = t; k < 2048; k += 256) {
            unsigned int wd = fvu[k];
            unsigned int h0 = wd & 0xffffu, h1 = wd >> 16;
            unsigned int e0 = (h0 >> 7) & 0xffu, e1 = (h1 >> 7) & 0xffu;
            c += (h0 == 0u || (e0 >= 100u && e0 <= 135u)) ? 1 : 0;
            c += (h1 == 0u || (e1 >= 100u && e1 <= 135u)) ? 1 : 0;
        }
        atomicAdd(&s_cnt, c);
        int lb = 0;
        for (int k = t; k < mwords; k += 256) {
            unsigned int wd = mu[k];
            if (wd > 1u) lb |= 1;
            if ((k & 1) && wd != 0u) lb |= 2;
            unsigned int lo = wd & 0xffffu, hi = wd >> 16;
            if (!((lo == 0u || lo == 0x3f80u) && (hi == 0u || hi == 0x3f80u))) lb |= 4;
            if (lo == 0x3f80u) lb |= 8;
        }
        if (lb) atomicOr(&s_bits, lb);
    }
    __syncthreads();
    int bts = s_bits;
    int fm  = (!(bts & 1)) ? ((bts & 2) ? 0 : 3)
                           : ((!(bts & 4)) ? ((bts & 8) ? 2 : 4) : 1);
    int isf = (s_cnt < 3900) ? 1 : 0;               // bf16 ~4096 hits, f32 ~2335
    if (bid == 0 && t == 0) { flags[0] = fm; flags[1] = isf; }

    if (bid < 512) {
        __shared__ f16 sfv[15360];                  // [(c*12+h)*20 + x]
        __shared__ int sx[756];
        __shared__ unsigned char sm[756];
        int b = bid >> 4, n0 = (bid & 15) * 63;
        int rows = min(63, 1000 - n0);
        if (isf) {                                  // f32: 3840 float4
            const float4* src = (const float4*)fv + (long)b * 3840;
            for (int k = t; k < 3840; k += 256) {
                float4 v = src[k];
                f16x4 h; h[0] = (f16)v.x; h[1] = (f16)v.y; h[2] = (f16)v.z; h[3] = (f16)v.w;
                *(f16x4*)&sfv[k * 4] = h;
            }
        } else {                                    // bf16: 1920 uint4
            const uint4* src = (const uint4*)fv + (long)b * 1920;
            for (int k = t; k < 1920; k += 256) {
                uint4 v = src[k];
                unsigned int wv[4] = {v.x, v.y, v.z, v.w};
                f16x8 h;
                #pragma unroll
                for (int j = 0; j < 4; j++) {
                    h[2 * j]     = (f16)__uint_as_float((wv[j] & 0xffffu) << 16);
                    h[2 * j + 1] = (f16)__uint_as_float(wv[j] & 0xffff0000u);
                }
                *(f16x8*)&sfv[k * 8] = h;
            }
        }
        for (int k = t; k < rows * 12; k += 256) {
            int n = k / 12, h = k - n * 12;
            sx[k] = x_idx[(long)(n0 + n) * xstride + h];
            long mb = (long)(n0 + n) * mstride + h;
            int mv;
            if (fm == 0)      mv = ((const int*)maskp)[mb] != 0;
            else if (fm == 1) mv = ((const unsigned char*)maskp)[mb] != 0;
            else if (fm == 2) mv = ((const unsigned short*)maskp)[mb] != 0;
            else if (fm == 3) mv = ((const int*)maskp)[mb * 2] != 0;
            else              mv = ((const unsigned int*)maskp)[mb] != 0;
            sm[k] = (unsigned char)mv;
        }
        __syncthreads();
        for (int q = t; q < rows * 192; q += 256) {
            int n = q / 192, r = q - n * 192;
            int e0 = r * 4;
            f16x4 v;
            #pragma unroll
            for (int j = 0; j < 4; j++) {
                int e = e0 + j;
                int h = e % 12;
                int kk = n * 12 + h;
                v[j] = sm[kk] ? (f16)0.f : sfv[e * 20 + sx[kk]];
            }
            *(f16x4*)(feat + ((long)(b * 1000 + n0 + n)) * 768 + e0) = v;
        }
    } else if (bid < 1280) {
        // attn_w (768 x 999, ld 999) -> awT (1024 x 768, ld 768), rows>=999 zero
        __shared__ f16 tile[32][33];
        int tid = bid - 512;
        int c0 = (tid % 32) * 32, r0 = (tid / 32) * 32;
        int tx = t & 31, ty = t >> 5;
        #pragma unroll
        for (int i = ty; i < 32; i += 8) {
            int r = r0 + i, c = c0 + tx;
            float v = 0.f;
            if (r < 768 && c < 999) v = ldf(attn_w, (long)r * 999 + c, isf);
            tile[i][tx] = (f16)v;
        }
        __syncthreads();
        #pragma unroll
        for (int i = ty; i < 32; i += 8) {
            int oc = c0 + i, orw = r0 + tx;
            awT[(long)oc * 768 + orw] = tile[tx][i];
        }
    } else {
        int idx = (bid - 1280) * 256 + t;           // 128*1536 = 196608
        if (idx < 128 * 1536) {
            int c = idx / 1536, k = idx - c * 1536;
            float v = 0.f;
            if (c < 2)       v = ldf(cls_w, (long)k * 2 + c, isf);
            else if (c < 75) v = ldf(reg_w, (long)k * 73 + (c - 2), isf);
            wcT[idx] = (f16)v;                       // wcT[c][k], ld 1536
        }
        if (idx < 75)
            biasc[idx] = (idx < 2) ? ldf(cls_b, idx, isf) : ldf(reg_b, idx - 2, isf);
        if (idx < 1024)
            abf32[idx] = (idx < 999) ? ldf(attn_b, idx, isf) : 0.f;
    }
}

// ---------------- post: feat->featT transpose + softmax-scatter (one dispatch) ----------------
__global__ __launch_bounds__(256) void post_kernel(
    f16* __restrict__ buf, const float* __restrict__ abf32,
    const f16* __restrict__ feat, f16* __restrict__ featT)
{
    int bid = blockIdx.x;
    int t = threadIdx.x;
    if (bid < 24576) {
        if (!featT) return;
        __shared__ f16 tile[32][33];
        int bx = bid % 24, rq = bid / 24;
        int by = rq % 32, bz = rq / 32;
        int c0 = bx * 32, r0 = by * 32;
        int tx = t & 31, ty = t >> 5;
        const f16* src = feat + (long)bz * 768000;
        #pragma unroll
        for (int i = ty; i < 32; i += 8) {
            int r = r0 + i, c = c0 + tx;
            f16 v = (f16)0.f;
            if (r < 1000) v = src[(long)r * 768 + c];
            tile[i][tx] = v;
        }
        __syncthreads();
        f16* dst = featT + (long)bz * 786432;
        #pragma unroll
        for (int i = ty; i < 32; i += 8) {
            int oc = c0 + i, orw = r0 + tx;
            dst[(long)oc * 1024 + orw] = tile[tx][i];
        }
    } else {
        int rid = bid - 24576;
        int i = rid % 1000, b = rid / 1000;
        f16* row = buf + ((long)(b * 1000 + i)) * 1024;
        __shared__ float red[8];
        int k0 = t * 4;
        f16x4 rv = *(const f16x4*)(row + k0);        // all reads before any write
        float4 ab = *(const float4*)(abf32 + k0);
        float abv[4] = {ab.x, ab.y, ab.z, ab.w};
        float v[4];
        float lmax = -3.4e38f;
        #pragma unroll
        for (int j = 0; j < 4; j++) {
            int k = k0 + j;
            float x = (k < 999) ? (float)rv[j] + abv[j] : -3.4e38f;
            v[j] = x;
            lmax = fmaxf(lmax, x);
        }
        #pragma unroll
        for (int o = 32; o > 0; o >>= 1) lmax = fmaxf(lmax, __shfl_down(lmax, o, 64));
        if ((t & 63) == 0) red[t >> 6] = lmax;
        __syncthreads();
        float gmax = fmaxf(fmaxf(red[0], red[1]), fmaxf(red[2], red[3]));
        float lsum = 0.f;
        #pragma unroll
        for (int j = 0; j < 4; j++) {
            int k = k0 + j;
            float e = (k < 999) ? __expf(v[j] - gmax) : 0.f;
            v[j] = e;
            lsum += e;
        }
        #pragma unroll
        for (int o = 32; o > 0; o >>= 1) lsum += __shfl_down(lsum, o, 64);
        if ((t & 63) == 0) red[4 + (t >> 6)] = lsum;
        __syncthreads();
        float inv = 1.f / (red[4] + red[5] + red[6] + red[7]);
        #pragma unroll
        for (int j = 0; j < 4; j++) {
            int k = k0 + j;
            if (k < 999) row[k + (k >= i ? 1 : 0)] = (f16)(v[j] * inv);
        }
        if (t == 0) row[i] = (f16)0.f;               // zero diagonal
    }
}

// ---------------- MFMA GEMM ----------------
// !BKM: single-buffer BK-chunk K-loop, global_load_lds(16B), XOR-swizzled LDS.
// BG: B fragments straight from global into VGPRs (B must be L2-hot & row-padded);
//     A-only LDS. B loads issued BEFORE the staging barrier -> fly across the drain.
//     NOTE: B row is GLOBAL (n0 + local r) — r13 bug was missing n0 (latent for n0==0).
// SWZ: 0 none; 2 GEMM1 m-group->XCD; 3 GEMM2 batch->XCD. NT: persistent passes.
enum { OUT_F16 = 0, OUT_FINAL = 1 };

template<int MODE, bool CAT, bool BKM, int TM, int TN, int BK, int SWZ, bool BG, int NT>
__global__ __launch_bounds__(256, 2) void gemm_kernel(
    const f16* __restrict__ A0, const f16* __restrict__ A20, int lda,
    const f16* __restrict__ Bt0, int ldb,
    void* __restrict__ Cout, int ldc,
    int M, int Nc, int K,
    long sA, long sB, long sC,
    const float* __restrict__ bias, const void* __restrict__ anchors,
    const int* __restrict__ flags)
{
    int t = threadIdx.x;
    int w = t >> 6, lane = t & 63;
    int lr = lane & 15, lq = lane >> 4;
    constexpr int NJ = (TM == 128 && TN == 256) ? 8 : ((TN == 256) ? 4 : ((TM == 128) ? 4 : 2));
    int wm = (TM == 128) ? (w & 1) * 64 : 0;
    int wn;
    if constexpr (TM == 128 && TN == 256) wn = (w >> 1) * 128;
    else if constexpr (TN == 256)         wn = w * 64;
    else if constexpr (TM == 128)         wn = (w >> 1) * 64;
    else                                  wn = w * 32;

    for (int tp = 0; tp < NT; tp++) {
        int bx, by, bz;
        if constexpr (SWZ == 2) {
            int bid = blockIdx.x + tp * 512;
            int xcd = bid & 7, s = bid >> 3;
            int g = xcd + 8 * (s >> 2);              // XCD owns groups g == xcd (mod 8)
            if (g >= (M + TM - 1) / TM) continue;
            by = g; bx = s & 3; bz = 0;
        } else if constexpr (SWZ == 3) {             // 768 tiles: 8 XCD x 4 batch x (8m x 3n)
            int bid = blockIdx.x + tp * 512;
            if (bid >= 768) continue;
            int xcd = bid & 7, s = bid >> 3;         // s in [0,96)
            bz = xcd * 4 + s / 24;
            int wv = s % 24;
            by = wv / 3; bx = wv - by * 3;
        } else { bx = blockIdx.x; by = blockIdx.y; bz = blockIdx.z; }

        int m0 = by * TM, n0 = bx * TN;
        int z = bz;
        const f16* A  = A0 + (long)z * sA;
        const f16* A2 = CAT ? (A20 + (long)z * sA) : nullptr;
        const f16* Bt = Bt0 + (long)z * sB;

        const f32x4 zero4 = {0.f, 0.f, 0.f, 0.f};
        f32x4 acc[4][NJ];
        #pragma unroll
        for (int i = 0; i < 4; i++)
            #pragma unroll
            for (int j = 0; j < NJ; j++) acc[i][j] = zero4;

        if constexpr (BG) {
            // A staged to LDS; B fragments straight from global (L2-hot, row-padded)
            constexpr int CH  = BK / 8;
            constexpr int AI  = TM * BK / 2048;
            constexpr int RPO = 2048 / BK;
            __shared__ __align__(16) f16 As[TM * BK];
            int row0 = t / CH, slot = t % CH;
            int csw = slot ^ (row0 & (CH - 1));
            long aoffB = (long)(m0 + row0) * lda + csw * 8;
            for (int k0 = 0; k0 < K; k0 += BK) {
                const f16* Ak = A; int kk = k0;
                if (CAT && k0 >= 768) { Ak = A2; kk = k0 - 768; }
                __syncthreads();
                #pragma unroll
                for (int i = 0; i < AI; i++)
                    gl2lds16(Ak + aoffB + (long)(i * RPO) * lda + kk, &As[i * 2048 + w * 512]);
                // B loads issued before the barrier -> in flight across the vmcnt drain
                f16x8 ball[BK / 32][NJ];
                #pragma unroll
                for (int ks = 0; ks < BK / 32; ks++)
                    #pragma unroll
                    for (int j = 0; j < NJ; j++) {
                        int r = n0 + wn + j * 16 + lr;   // GLOBAL row (fix: + n0)
                        ball[ks][j] = *(const f16x8*)(Bt + (long)r * ldb + k0 + (ks * 4 + lq) * 8);
                    }
                __syncthreads();
                #pragma unroll
                for (int ks = 0; ks < BK / 32; ks++) {
                    f16x8 af[4];
                    #pragma unroll
                    for (int i = 0; i < 4; i++) {
                        int r = wm + i * 16 + lr;
                        int cc = (lq + ks * 4) ^ (r & (CH - 1));
                        af[i] = *(const f16x8*)&As[r * BK + cc * 8];
                    }
                    #pragma unroll
                    for (int i = 0; i < 4; i++)
                        #pragma unroll
                        for (int j = 0; j < NJ; j++)
                            acc[i][j] = __builtin_amdgcn_mfma_f32_16x16x32_f16(af[i], ball[ks][j], acc[i][j], 0, 0, 0);
                }
            }
        } else if constexpr (!BKM) {
            constexpr int CH  = BK / 8;
            constexpr int AI  = TM * BK / 2048;
            constexpr int BI  = TN * BK / 2048;
            constexpr int RPO = 2048 / BK;
            __shared__ __align__(16) f16 As[TM * BK];
            __shared__ __align__(16) f16 Bs[TN * BK];
            int row0 = t / CH, slot = t % CH;
            int csw = slot ^ (row0 & (CH - 1));
            long aoffB = (long)(m0 + row0) * lda + csw * 8;
            long boffB = (long)(n0 + row0) * ldb + csw * 8;
            for (int k0 = 0; k0 < K; k0 += BK) {
                const f16* Ak = A; int kk = k0;
                if (CAT && k0 >= 768) { Ak = A2; kk = k0 - 768; }
                __syncthreads();
                #pragma unroll
                for (int i = 0; i < AI; i++)
                    gl2lds16(Ak + aoffB + (long)(i * RPO) * lda + kk, &As[i * 2048 + w * 512]);
                #pragma unroll
                for (int i = 0; i < BI; i++)
                    gl2lds16(Bt + boffB + (long)(i * RPO) * ldb + k0, &Bs[i * 2048 + w * 512]);
                __syncthreads();                     // drains vmcnt before barrier
                #pragma unroll
                for (int ks = 0; ks < BK / 32; ks++) {
                    f16x8 af[4], bfr[NJ];
                    #pragma unroll
                    for (int i = 0; i < 4; i++) {
                        int r = wm + i * 16 + lr;
                        int cc = (lq + ks * 4) ^ (r & (CH - 1));
                        af[i] = *(const f16x8*)&As[r * BK + cc * 8];
                    }
                    #pragma unroll
                    for (int j = 0; j < NJ; j++) {
                        int r = wn + j * 16 + lr;
                        int cc = (lq + ks * 4) ^ (r & (CH - 1));
                        bfr[j] = *(const f16x8*)&Bs[r * BK + cc * 8];
                    }
                    #pragma unroll
                    for (int i = 0; i < 4; i++)
                        #pragma unroll
                        for (int j = 0; j < NJ; j++)
                            acc[i][j] = __builtin_amdgcn_mfma_f32_16x16x32_f16(af[i], bfr[j], acc[i][j], 0, 0, 0);
                }
            }
        } else {
            __shared__ __align__(16) f16 As[128 * 40];
            __shared__ __align__(16) f16 Bs[32 * 132];
            const f16x8 zero8 = {(f16)0, (f16)0, (f16)0, (f16)0, (f16)0, (f16)0, (f16)0, (f16)0};
            const f16x4 zero4h = {(f16)0, (f16)0, (f16)0, (f16)0};
            for (int k0 = 0; k0 < K; k0 += 32) {
                __syncthreads();
                #pragma unroll
                for (int i = 0; i < 2; i++) {
                    int q = t + i * 256;
                    { int row = q >> 2, kc = (q & 3) * 8;
                      f16x8 av = zero8;
                      if ((m0 + row) < M && (k0 + kc) < K)
                          av = *(const f16x8*)(A + (long)(m0 + row) * lda + k0 + kc);
                      *(f16x8*)&As[row * 40 + kc] = av; }
                    { int kr = q >> 4, nc = (q & 15) * 8;
                      f16x4 b0 = zero4h, b1 = zero4h;
                      if ((k0 + kr) < K && (n0 + nc) < Nc) {
                          const f16* p2 = Bt + (long)(k0 + kr) * ldb + n0 + nc;
                          b0 = *(const f16x4*)p2;
                          b1 = *(const f16x4*)(p2 + 4);
                      }
                      *(f16x4*)&Bs[kr * 132 + nc]     = b0;
                      *(f16x4*)&Bs[kr * 132 + nc + 4] = b1; }
                }
                __syncthreads();
                f16x8 af[4], bfr[NJ];
                #pragma unroll
                for (int i = 0; i < 4; i++)
                    af[i] = *(const f16x8*)&As[(wm + i * 16 + lr) * 40 + lq * 8];
                #pragma unroll
                for (int j = 0; j < NJ; j++)
                    #pragma unroll
                    for (int jj = 0; jj < 8; jj++)
                        bfr[j][jj] = Bs[(lq * 8 + jj) * 132 + wn + j * 16 + lr];
                #pragma unroll
                for (int i = 0; i < 4; i++)
                    #pragma unroll
                    for (int j = 0; j < NJ; j++)
                        acc[i][j] = __builtin_amdgcn_mfma_f32_16x16x32_f16(af[i], bfr[j], acc[i][j], 0, 0, 0);
            }
        }

        int isf = (MODE == OUT_FINAL) ? flags[1] : 0;
        #pragma unroll
        for (int i = 0; i < 4; i++) {
            #pragma unroll
            for (int j = 0; j < NJ; j++) {
                #pragma unroll
                for (int r = 0; r < 4; r++) {
                    int gm = m0 + wm + i * 16 + lq * 4 + r;   // C/D: row = quad*4+reg
                    int gn = n0 + wn + j * 16 + lr;           //      col = lane&15
                    if (MODE == OUT_F16) {
                        if (gm < M && gn < Nc)
                            ((f16*)Cout)[(long)z * sC + (long)gm * ldc + gn] = (f16)acc[i][j][r];
                    } else {
                        if (gn < Nc) {                         // Nc=75 real cols
                            float v = acc[i][j][r] + bias[gn];
                            int oc = (gn < 2) ? gn : gn + 2;   // skip anchor cols 2,3
                            if (gn >= 2) v += ldf(anchors, (long)(gm % 1000) * 77 + oc, isf);
                            stf(Cout, (long)gm * 77 + oc, isf, v);
                        } else if (gn < 77) {                  // wasted lanes fill anchor cols 2,3
                            int oc = gn - 73;                  // 75->2, 76->3
                            stf(Cout, (long)gm * 77 + oc, isf,
                                ldf(anchors, (long)(gm % 1000) * 77 + oc, isf));
                        }
                    }
                }
            }
        }
    }
}

extern "C" void kernel_launch(void* const* d_in, const int* in_sizes, int n_in,
                              void* d_out, int out_size, void* d_ws, size_t ws_size,
                              hipStream_t stream)
{
    const void* fv      = d_in[0];
    const void* attn_w  = d_in[1];
    const void* attn_b  = d_in[2];
    const void* cls_w   = d_in[3];
    const void* cls_b   = d_in[4];
    const void* reg_w   = d_in[5];
    const void* reg_b   = d_in[6];
    const void* anchors = d_in[7];
    const int*  x_idx   = (const int*)d_in[10];
    const void* maskp   = d_in[11];
    int xstride = (in_sizes[10] < 768000) ? 12 : 768;   // un-broadcast fallback
    int mstride = (in_sizes[11] < 768000) ? 12 : 768;
    int mwords  = in_sizes[11] / 4;                      // int8 worst case, stay in bounds
    if (mwords > 4096) mwords = 4096;

    char* ws = (char*)d_ws;
    f16*   logits = (f16*)(ws + OFF_LOGITS);
    f16*   feat   = (f16*)(ws + OFF_FEAT);
    f16*   attf   = (f16*)(ws + OFF_ATTF);
    f16*   awT    = (f16*)(ws + OFF_AWT);
    f16*   wcT    = (f16*)(ws + OFF_WCT);
    float* biasc  = (float*)(ws + OFF_BIAS);
    float* abf32  = (float*)(ws + OFF_AB);
    int*   flags  = (int*)(ws + OFF_FLAG);
    f16*   featT  = (f16*)(ws + OFF_FEATT);
    bool bigws = ws_size >= (size_t)NEED_A;

    front_kernel<<<dim3(2048), dim3(256), 0, stream>>>(
        fv, x_idx, maskp, mwords, flags, xstride, mstride, feat,
        attn_w, cls_w, cls_b, reg_w, reg_b, attn_b, awT, wcT, biasc, abf32);

    // GEMM1: logits = feat @ attn_w  (M=32000, N=1024 padded, K=768), BK=64
    // BG: B=awT (1.5 MB, replicated L2-hot in every XCD) straight to VGPRs
    gemm_kernel<OUT_F16, false, false, 128, 256, 64, 2, true, 1><<<dim3(1024), dim3(256), 0, stream>>>(
        feat, nullptr, 768, awT, 768, logits, 1024, 32000, 1024, 768, 0, 0, 0,
        nullptr, nullptr, flags);
    // transpose feat->featT + softmax-scatter in one dispatch
    post_kernel<<<dim3(24576 + 32000), dim3(256), 0, stream>>>(
        logits, abf32, feat, bigws ? featT : nullptr);
    // GEMM2 (batched): att_feat = S @ feat  (M=1000, N=768, K=1024 padded, 32 batches)
    // BG: B=featT (1.5 MB/batch, XCD-local L2 via SWZ=3); NT=2 persistence
    if (bigws) {
        gemm_kernel<OUT_F16, false, false, 128, 256, 64, 3, true, 2><<<dim3(512), dim3(256), 0, stream>>>(
            logits, nullptr, 1024, featT, 1024, attf, 768, 1000, 768, 1024,
            1024000L, 786432L, 768000L, nullptr, nullptr, flags);
    } else {
        gemm_kernel<OUT_F16, false, true, 128, 128, 32, 0, false, 1><<<dim3(6, 8, 32), dim3(256), 0, stream>>>(
            logits, nullptr, 1024, feat, 768, attf, 768, 1000, 768, 1000,
            1024000L, 768000L, 768000L, nullptr, nullptr, flags);
    }
    // GEMM3: out = [att_feat | feat] @ Wc, fused epilogue; BG path (B=wcT from L2),
    // A-only LDS (16 KB), BK=128, TM=64/TN=128 -> 500 blocks
    gemm_kernel<OUT_FINAL, true, false, 64, 128, 128, 0, true, 1><<<dim3(1, 500, 1), dim3(256), 0, stream>>>(
        attf, feat, 768, wcT, 1536, d_out, 77, 32000, 75, 1536, 0, 0, 0,
        biasc, anchors, flags);
}

// Round 15
// 341.183 us; speedup vs baseline: 1.2950x; 1.2950x over previous
//
#include <hip/hip_runtime.h>
#include <hip/hip_bf16.h>

typedef _Float16 f16;
typedef _Float16 f16x4 __attribute__((ext_vector_type(4)));
typedef _Float16 f16x8 __attribute__((ext_vector_type(8)));
typedef float    f32x4 __attribute__((ext_vector_type(4)));

static __device__ __forceinline__ float bf2f(__hip_bfloat16 x) { return __bfloat162float(x); }
// dual-dtype float load/store: f32flag=1 -> float*, else bf16*
static __device__ __forceinline__ float ldf(const void* p, long i, int f32flag) {
    return f32flag ? ((const float*)p)[i] : bf2f(((const __hip_bfloat16*)p)[i]);
}
static __device__ __forceinline__ void stf(void* p, long i, int f32flag, float v) {
    if (f32flag) ((float*)p)[i] = v;
    else ((__hip_bfloat16*)p)[i] = __float2bfloat16(v);
}
// async global->LDS, 16B per lane; LDS dest is wave-uniform base + lane*16
static __device__ __forceinline__ void gl2lds16(const f16* g, f16* l) {
    __builtin_amdgcn_global_load_lds(
        (const __attribute__((address_space(1))) unsigned int*)(const void*)g,
        (__attribute__((address_space(3))) unsigned int*)(void*)l, 16, 0, 0);
}

// ---------------- workspace layout (bytes) ----------------
#define OFF_LOGITS 0L                               // S/logits: 32000 x 1024 f16
#define SZ_LOGITS  (32000L * 1024 * 2)
#define OFF_FEAT   (OFF_LOGITS + SZ_LOGITS)         // feat: 32000 x 768 f16
#define SZ_FEAT    (32000L * 768 * 2)
#define OFF_ATTF   (OFF_FEAT + SZ_FEAT)             // att_feat: 32000 x 768 f16
#define SZ_ATTF    (32000L * 768 * 2)
#define OFF_AWT    (OFF_ATTF + SZ_ATTF)             // attn_w^T: 1024 x 768 f16 (rows>=999 zero)
#define SZ_AWT     (1024L * 768 * 2)
#define OFF_WCT    (OFF_AWT + SZ_AWT)               // Wc^T: 128 x 1536 f16 (rows>=75 zero)
#define SZ_WCT     (128L * 1536 * 2)
#define OFF_BIAS   (OFF_WCT + SZ_WCT)               // f32[128]
#define OFF_AB     (OFF_BIAS + 512)                 // attn_b as f32[1024]
#define OFF_FLAG   (OFF_AB + 4096)                  // int flags[2]
#define OFF_FEATT  (OFF_FLAG + 64)                  // feat^T per batch: 32 x 768 x 1024 f16
#define SZ_FEATT   (32L * 768 * 1024 * 2)
#define NEED_A     (OFF_FEATT + SZ_FEATT)           // ~216 MB

// ---------------- front: inline dtype detection + build_feat + awT + weight packing ----------------
// grid 2048: [0,512) feat gather; [512,1280) awT transpose; [1280,2048) wc/bias/abf32
__global__ __launch_bounds__(256) void front_kernel(
    const void* __restrict__ fv, const int* __restrict__ x_idx,
    const void* __restrict__ maskp, int mwords, int* __restrict__ flags,
    int xstride, int mstride, f16* __restrict__ feat,
    const void* __restrict__ attn_w,
    const void* __restrict__ cls_w, const void* __restrict__ cls_b,
    const void* __restrict__ reg_w, const void* __restrict__ reg_b,
    const void* __restrict__ attn_b,
    f16* __restrict__ awT, f16* __restrict__ wcT,
    float* __restrict__ biasc, float* __restrict__ abf32)
{
    int bid = blockIdx.x;
    int t = threadIdx.x;
    // ---- inline detection (uniform across block) ----
    __shared__ int s_cnt, s_bits;
    if (t == 0) { s_cnt = 0; s_bits = 0; }
    __syncthreads();
    {
        const unsigned int* fvu = (const unsigned int*)fv;
        const unsigned int* mu  = (const unsigned int*)maskp;
        int c = 0;
        for (int k = t; k < 2048; k += 256) {
            unsigned int wd = fvu[k];
            unsigned int h0 = wd & 0xffffu, h1 = wd >> 16;
            unsigned int e0 = (h0 >> 7) & 0xffu, e1 = (h1 >> 7) & 0xffu;
            c += (h0 == 0u || (e0 >= 100u && e0 <= 135u)) ? 1 : 0;
            c += (h1 == 0u || (e1 >= 100u && e1 <= 135u)) ? 1 : 0;
        }
        atomicAdd(&s_cnt, c);
        int lb = 0;
        for (int k = t; k < mwords; k += 256) {
            unsigned int wd = mu[k];
            if (wd > 1u) lb |= 1;
            if ((k & 1) && wd != 0u) lb |= 2;
            unsigned int lo = wd & 0xffffu, hi = wd >> 16;
            if (!((lo == 0u || lo == 0x3f80u) && (hi == 0u || hi == 0x3f80u))) lb |= 4;
            if (lo == 0x3f80u) lb |= 8;
        }
        if (lb) atomicOr(&s_bits, lb);
    }
    __syncthreads();
    int bts = s_bits;
    int fm  = (!(bts & 1)) ? ((bts & 2) ? 0 : 3)
                           : ((!(bts & 4)) ? ((bts & 8) ? 2 : 4) : 1);
    int isf = (s_cnt < 3900) ? 1 : 0;               // bf16 ~4096 hits, f32 ~2335
    if (bid == 0 && t == 0) { flags[0] = fm; flags[1] = isf; }

    if (bid < 512) {
        __shared__ f16 sfv[15360];                  // [(c*12+h)*20 + x]
        __shared__ int sx[756];
        __shared__ unsigned char sm[756];
        int b = bid >> 4, n0 = (bid & 15) * 63;
        int rows = min(63, 1000 - n0);
        if (isf) {                                  // f32: 3840 float4
            const float4* src = (const float4*)fv + (long)b * 3840;
            for (int k = t; k < 3840; k += 256) {
                float4 v = src[k];
                f16x4 h; h[0] = (f16)v.x; h[1] = (f16)v.y; h[2] = (f16)v.z; h[3] = (f16)v.w;
                *(f16x4*)&sfv[k * 4] = h;
            }
        } else {                                    // bf16: 1920 uint4
            const uint4* src = (const uint4*)fv + (long)b * 1920;
            for (int k = t; k < 1920; k += 256) {
                uint4 v = src[k];
                unsigned int wv[4] = {v.x, v.y, v.z, v.w};
                f16x8 h;
                #pragma unroll
                for (int j = 0; j < 4; j++) {
                    h[2 * j]     = (f16)__uint_as_float((wv[j] & 0xffffu) << 16);
                    h[2 * j + 1] = (f16)__uint_as_float(wv[j] & 0xffff0000u);
                }
                *(f16x8*)&sfv[k * 8] = h;
            }
        }
        for (int k = t; k < rows * 12; k += 256) {
            int n = k / 12, h = k - n * 12;
            sx[k] = x_idx[(long)(n0 + n) * xstride + h];
            long mb = (long)(n0 + n) * mstride + h;
            int mv;
            if (fm == 0)      mv = ((const int*)maskp)[mb] != 0;
            else if (fm == 1) mv = ((const unsigned char*)maskp)[mb] != 0;
            else if (fm == 2) mv = ((const unsigned short*)maskp)[mb] != 0;
            else if (fm == 3) mv = ((const int*)maskp)[mb * 2] != 0;
            else              mv = ((const unsigned int*)maskp)[mb] != 0;
            sm[k] = (unsigned char)mv;
        }
        __syncthreads();
        for (int q = t; q < rows * 192; q += 256) {
            int n = q / 192, r = q - n * 192;
            int e0 = r * 4;
            f16x4 v;
            #pragma unroll
            for (int j = 0; j < 4; j++) {
                int e = e0 + j;
                int h = e % 12;
                int kk = n * 12 + h;
                v[j] = sm[kk] ? (f16)0.f : sfv[e * 20 + sx[kk]];
            }
            *(f16x4*)(feat + ((long)(b * 1000 + n0 + n)) * 768 + e0) = v;
        }
    } else if (bid < 1280) {
        // attn_w (768 x 999, ld 999) -> awT (1024 x 768, ld 768), rows>=999 zero
        __shared__ f16 tile[32][33];
        int tid = bid - 512;
        int c0 = (tid % 32) * 32, r0 = (tid / 32) * 32;
        int tx = t & 31, ty = t >> 5;
        #pragma unroll
        for (int i = ty; i < 32; i += 8) {
            int r = r0 + i, c = c0 + tx;
            float v = 0.f;
            if (r < 768 && c < 999) v = ldf(attn_w, (long)r * 999 + c, isf);
            tile[i][tx] = (f16)v;
        }
        __syncthreads();
        #pragma unroll
        for (int i = ty; i < 32; i += 8) {
            int oc = c0 + i, orw = r0 + tx;
            awT[(long)oc * 768 + orw] = tile[tx][i];
        }
    } else {
        int idx = (bid - 1280) * 256 + t;           // 128*1536 = 196608
        if (idx < 128 * 1536) {
            int c = idx / 1536, k = idx - c * 1536;
            float v = 0.f;
            if (c < 2)       v = ldf(cls_w, (long)k * 2 + c, isf);
            else if (c < 75) v = ldf(reg_w, (long)k * 73 + (c - 2), isf);
            wcT[idx] = (f16)v;                       // wcT[c][k], ld 1536
        }
        if (idx < 75)
            biasc[idx] = (idx < 2) ? ldf(cls_b, idx, isf) : ldf(reg_b, idx - 2, isf);
        if (idx < 1024)
            abf32[idx] = (idx < 999) ? ldf(attn_b, idx, isf) : 0.f;
    }
}

// ---------------- post: feat->featT transpose + softmax-scatter (one dispatch) ----------------
__global__ __launch_bounds__(256) void post_kernel(
    f16* __restrict__ buf, const float* __restrict__ abf32,
    const f16* __restrict__ feat, f16* __restrict__ featT)
{
    int bid = blockIdx.x;
    int t = threadIdx.x;
    if (bid < 24576) {
        if (!featT) return;
        __shared__ f16 tile[32][33];
        int bx = bid % 24, rq = bid / 24;
        int by = rq % 32, bz = rq / 32;
        int c0 = bx * 32, r0 = by * 32;
        int tx = t & 31, ty = t >> 5;
        const f16* src = feat + (long)bz * 768000;
        #pragma unroll
        for (int i = ty; i < 32; i += 8) {
            int r = r0 + i, c = c0 + tx;
            f16 v = (f16)0.f;
            if (r < 1000) v = src[(long)r * 768 + c];
            tile[i][tx] = v;
        }
        __syncthreads();
        f16* dst = featT + (long)bz * 786432;
        #pragma unroll
        for (int i = ty; i < 32; i += 8) {
            int oc = c0 + i, orw = r0 + tx;
            dst[(long)oc * 1024 + orw] = tile[tx][i];
        }
    } else {
        int rid = bid - 24576;
        int i = rid % 1000, b = rid / 1000;
        f16* row = buf + ((long)(b * 1000 + i)) * 1024;
        __shared__ float red[8];
        int k0 = t * 4;
        f16x4 rv = *(const f16x4*)(row + k0);        // all reads before any write
        float4 ab = *(const float4*)(abf32 + k0);
        float abv[4] = {ab.x, ab.y, ab.z, ab.w};
        float v[4];
        float lmax = -3.4e38f;
        #pragma unroll
        for (int j = 0; j < 4; j++) {
            int k = k0 + j;
            float x = (k < 999) ? (float)rv[j] + abv[j] : -3.4e38f;
            v[j] = x;
            lmax = fmaxf(lmax, x);
        }
        #pragma unroll
        for (int o = 32; o > 0; o >>= 1) lmax = fmaxf(lmax, __shfl_down(lmax, o, 64));
        if ((t & 63) == 0) red[t >> 6] = lmax;
        __syncthreads();
        float gmax = fmaxf(fmaxf(red[0], red[1]), fmaxf(red[2], red[3]));
        float lsum = 0.f;
        #pragma unroll
        for (int j = 0; j < 4; j++) {
            int k = k0 + j;
            float e = (k < 999) ? __expf(v[j] - gmax) : 0.f;
            v[j] = e;
            lsum += e;
        }
        #pragma unroll
        for (int o = 32; o > 0; o >>= 1) lsum += __shfl_down(lsum, o, 64);
        if ((t & 63) == 0) red[4 + (t >> 6)] = lsum;
        __syncthreads();
        float inv = 1.f / (red[4] + red[5] + red[6] + red[7]);
        #pragma unroll
        for (int j = 0; j < 4; j++) {
            int k = k0 + j;
            if (k < 999) row[k + (k >= i ? 1 : 0)] = (f16)(v[j] * inv);
        }
        if (t == 0) row[i] = (f16)0.f;               // zero diagonal
    }
}

// ---------------- MFMA GEMM ----------------
// !BKM: single-buffer BK-chunk K-loop, global_load_lds(16B), XOR-swizzled LDS.
//   [measured r8-r14: this 2-barrier BK=64 structure is the optimum for these shapes;
//    manual vmcnt dbuf (r9), BG-from-L2 on wide tiles (r14), BK=128 all regressed]
// BG: B fragments straight from global (ONLY for narrow-TN L2-hot B, e.g. wcT; n0-aware).
// SWZ: 0 none; 2 GEMM1 m-group->XCD; 3 GEMM2 batch->XCD. NT: persistent passes.
enum { OUT_F16 = 0, OUT_FINAL = 1 };

template<int MODE, bool CAT, bool BKM, int TM, int TN, int BK, int SWZ, bool BG, int NT>
__global__ __launch_bounds__(256, 2) void gemm_kernel(
    const f16* __restrict__ A0, const f16* __restrict__ A20, int lda,
    const f16* __restrict__ Bt0, int ldb,
    void* __restrict__ Cout, int ldc,
    int M, int Nc, int K,
    long sA, long sB, long sC,
    const float* __restrict__ bias, const void* __restrict__ anchors,
    const int* __restrict__ flags)
{
    int t = threadIdx.x;
    int w = t >> 6, lane = t & 63;
    int lr = lane & 15, lq = lane >> 4;
    constexpr int NJ = (TM == 128 && TN == 256) ? 8 : ((TN == 256) ? 4 : ((TM == 128) ? 4 : 2));
    int wm = (TM == 128) ? (w & 1) * 64 : 0;
    int wn;
    if constexpr (TM == 128 && TN == 256) wn = (w >> 1) * 128;
    else if constexpr (TN == 256)         wn = w * 64;
    else if constexpr (TM == 128)         wn = (w >> 1) * 64;
    else                                  wn = w * 32;

    for (int tp = 0; tp < NT; tp++) {
        int bx, by, bz;
        if constexpr (SWZ == 2) {
            int bid = blockIdx.x + tp * 512;
            int xcd = bid & 7, s = bid >> 3;
            int g = xcd + 8 * (s >> 2);              // XCD owns groups g == xcd (mod 8)
            if (g >= (M + TM - 1) / TM) continue;
            by = g; bx = s & 3; bz = 0;
        } else if constexpr (SWZ == 3) {             // 768 tiles: 8 XCD x 4 batch x (8m x 3n)
            int bid = blockIdx.x + tp * 512;
            if (bid >= 768) continue;
            int xcd = bid & 7, s = bid >> 3;         // s in [0,96)
            bz = xcd * 4 + s / 24;
            int wv = s % 24;
            by = wv / 3; bx = wv - by * 3;
        } else { bx = blockIdx.x; by = blockIdx.y; bz = blockIdx.z; }

        int m0 = by * TM, n0 = bx * TN;
        int z = bz;
        const f16* A  = A0 + (long)z * sA;
        const f16* A2 = CAT ? (A20 + (long)z * sA) : nullptr;
        const f16* Bt = Bt0 + (long)z * sB;

        const f32x4 zero4 = {0.f, 0.f, 0.f, 0.f};
        f32x4 acc[4][NJ];
        #pragma unroll
        for (int i = 0; i < 4; i++)
            #pragma unroll
            for (int j = 0; j < NJ; j++) acc[i][j] = zero4;

        if constexpr (BG) {
            // A staged to LDS; B fragments straight from global (L2-hot, row-padded)
            constexpr int CH  = BK / 8;
            constexpr int AI  = TM * BK / 2048;
            constexpr int RPO = 2048 / BK;
            __shared__ __align__(16) f16 As[TM * BK];
            int row0 = t / CH, slot = t % CH;
            int csw = slot ^ (row0 & (CH - 1));
            long aoffB = (long)(m0 + row0) * lda + csw * 8;
            for (int k0 = 0; k0 < K; k0 += BK) {
                const f16* Ak = A; int kk = k0;
                if (CAT && k0 >= 768) { Ak = A2; kk = k0 - 768; }
                __syncthreads();
                #pragma unroll
                for (int i = 0; i < AI; i++)
                    gl2lds16(Ak + aoffB + (long)(i * RPO) * lda + kk, &As[i * 2048 + w * 512]);
                // B loads issued before the barrier -> in flight across the vmcnt drain
                f16x8 ball[BK / 32][NJ];
                #pragma unroll
                for (int ks = 0; ks < BK / 32; ks++)
                    #pragma unroll
                    for (int j = 0; j < NJ; j++) {
                        int r = n0 + wn + j * 16 + lr;   // GLOBAL row
                        ball[ks][j] = *(const f16x8*)(Bt + (long)r * ldb + k0 + (ks * 4 + lq) * 8);
                    }
                __syncthreads();
                #pragma unroll
                for (int ks = 0; ks < BK / 32; ks++) {
                    f16x8 af[4];
                    #pragma unroll
                    for (int i = 0; i < 4; i++) {
                        int r = wm + i * 16 + lr;
                        int cc = (lq + ks * 4) ^ (r & (CH - 1));
                        af[i] = *(const f16x8*)&As[r * BK + cc * 8];
                    }
                    #pragma unroll
                    for (int i = 0; i < 4; i++)
                        #pragma unroll
                        for (int j = 0; j < NJ; j++)
                            acc[i][j] = __builtin_amdgcn_mfma_f32_16x16x32_f16(af[i], ball[ks][j], acc[i][j], 0, 0, 0);
                }
            }
        } else if constexpr (!BKM) {
            constexpr int CH  = BK / 8;
            constexpr int AI  = TM * BK / 2048;
            constexpr int BI  = TN * BK / 2048;
            constexpr int RPO = 2048 / BK;
            __shared__ __align__(16) f16 As[TM * BK];
            __shared__ __align__(16) f16 Bs[TN * BK];
            int row0 = t / CH, slot = t % CH;
            int csw = slot ^ (row0 & (CH - 1));
            long aoffB = (long)(m0 + row0) * lda + csw * 8;
            long boffB = (long)(n0 + row0) * ldb + csw * 8;
            for (int k0 = 0; k0 < K; k0 += BK) {
                const f16* Ak = A; int kk = k0;
                if (CAT && k0 >= 768) { Ak = A2; kk = k0 - 768; }
                __syncthreads();
                #pragma unroll
                for (int i = 0; i < AI; i++)
                    gl2lds16(Ak + aoffB + (long)(i * RPO) * lda + kk, &As[i * 2048 + w * 512]);
                #pragma unroll
                for (int i = 0; i < BI; i++)
                    gl2lds16(Bt + boffB + (long)(i * RPO) * ldb + k0, &Bs[i * 2048 + w * 512]);
                __syncthreads();                     // drains vmcnt before barrier
                #pragma unroll
                for (int ks = 0; ks < BK / 32; ks++) {
                    f16x8 af[4], bfr[NJ];
                    #pragma unroll
                    for (int i = 0; i < 4; i++) {
                        int r = wm + i * 16 + lr;
                        int cc = (lq + ks * 4) ^ (r & (CH - 1));
                        af[i] = *(const f16x8*)&As[r * BK + cc * 8];
                    }
                    #pragma unroll
                    for (int j = 0; j < NJ; j++) {
                        int r = wn + j * 16 + lr;
                        int cc = (lq + ks * 4) ^ (r & (CH - 1));
                        bfr[j] = *(const f16x8*)&Bs[r * BK + cc * 8];
                    }
                    #pragma unroll
                    for (int i = 0; i < 4; i++)
                        #pragma unroll
                        for (int j = 0; j < NJ; j++)
                            acc[i][j] = __builtin_amdgcn_mfma_f32_16x16x32_f16(af[i], bfr[j], acc[i][j], 0, 0, 0);
                }
            }
        } else {
            __shared__ __align__(16) f16 As[128 * 40];
            __shared__ __align__(16) f16 Bs[32 * 132];
            const f16x8 zero8 = {(f16)0, (f16)0, (f16)0, (f16)0, (f16)0, (f16)0, (f16)0, (f16)0};
            const f16x4 zero4h = {(f16)0, (f16)0, (f16)0, (f16)0};
            for (int k0 = 0; k0 < K; k0 += 32) {
                __syncthreads();
                #pragma unroll
                for (int i = 0; i < 2; i++) {
                    int q = t + i * 256;
                    { int row = q >> 2, kc = (q & 3) * 8;
                      f16x8 av = zero8;
                      if ((m0 + row) < M && (k0 + kc) < K)
                          av = *(const f16x8*)(A + (long)(m0 + row) * lda + k0 + kc);
                      *(f16x8*)&As[row * 40 + kc] = av; }
                    { int kr = q >> 4, nc = (q & 15) * 8;
                      f16x4 b0 = zero4h, b1 = zero4h;
                      if ((k0 + kr) < K && (n0 + nc) < Nc) {
                          const f16* p2 = Bt + (long)(k0 + kr) * ldb + n0 + nc;
                          b0 = *(const f16x4*)p2;
                          b1 = *(const f16x4*)(p2 + 4);
                      }
                      *(f16x4*)&Bs[kr * 132 + nc]     = b0;
                      *(f16x4*)&Bs[kr * 132 + nc + 4] = b1; }
                }
                __syncthreads();
                f16x8 af[4], bfr[NJ];
                #pragma unroll
                for (int i = 0; i < 4; i++)
                    af[i] = *(const f16x8*)&As[(wm + i * 16 + lr) * 40 + lq * 8];
                #pragma unroll
                for (int j = 0; j < NJ; j++)
                    #pragma unroll
                    for (int jj = 0; jj < 8; jj++)
                        bfr[j][jj] = Bs[(lq * 8 + jj) * 132 + wn + j * 16 + lr];
                #pragma unroll
                for (int i = 0; i < 4; i++)
                    #pragma unroll
                    for (int j = 0; j < NJ; j++)
                        acc[i][j] = __builtin_amdgcn_mfma_f32_16x16x32_f16(af[i], bfr[j], acc[i][j], 0, 0, 0);
            }
        }

        int isf = (MODE == OUT_FINAL) ? flags[1] : 0;
        #pragma unroll
        for (int i = 0; i < 4; i++) {
            #pragma unroll
            for (int j = 0; j < NJ; j++) {
                #pragma unroll
                for (int r = 0; r < 4; r++) {
                    int gm = m0 + wm + i * 16 + lq * 4 + r;   // C/D: row = quad*4+reg
                    int gn = n0 + wn + j * 16 + lr;           //      col = lane&15
                    if (MODE == OUT_F16) {
                        if (gm < M && gn < Nc)
                            ((f16*)Cout)[(long)z * sC + (long)gm * ldc + gn] = (f16)acc[i][j][r];
                    } else {
                        if (gn < Nc) {                         // Nc=75 real cols
                            float v = acc[i][j][r] + bias[gn];
                            int oc = (gn < 2) ? gn : gn + 2;   // skip anchor cols 2,3
                            if (gn >= 2) v += ldf(anchors, (long)(gm % 1000) * 77 + oc, isf);
                            stf(Cout, (long)gm * 77 + oc, isf, v);
                        } else if (gn < 77) {                  // wasted lanes fill anchor cols 2,3
                            int oc = gn - 73;                  // 75->2, 76->3
                            stf(Cout, (long)gm * 77 + oc, isf,
                                ldf(anchors, (long)(gm % 1000) * 77 + oc, isf));
                        }
                    }
                }
            }
        }
    }
}

extern "C" void kernel_launch(void* const* d_in, const int* in_sizes, int n_in,
                              void* d_out, int out_size, void* d_ws, size_t ws_size,
                              hipStream_t stream)
{
    const void* fv      = d_in[0];
    const void* attn_w  = d_in[1];
    const void* attn_b  = d_in[2];
    const void* cls_w   = d_in[3];
    const void* cls_b   = d_in[4];
    const void* reg_w   = d_in[5];
    const void* reg_b   = d_in[6];
    const void* anchors = d_in[7];
    const int*  x_idx   = (const int*)d_in[10];
    const void* maskp   = d_in[11];
    int xstride = (in_sizes[10] < 768000) ? 12 : 768;   // un-broadcast fallback
    int mstride = (in_sizes[11] < 768000) ? 12 : 768;
    int mwords  = in_sizes[11] / 4;                      // int8 worst case, stay in bounds
    if (mwords > 4096) mwords = 4096;

    char* ws = (char*)d_ws;
    f16*   logits = (f16*)(ws + OFF_LOGITS);
    f16*   feat   = (f16*)(ws + OFF_FEAT);
    f16*   attf   = (f16*)(ws + OFF_ATTF);
    f16*   awT    = (f16*)(ws + OFF_AWT);
    f16*   wcT    = (f16*)(ws + OFF_WCT);
    float* biasc  = (float*)(ws + OFF_BIAS);
    float* abf32  = (float*)(ws + OFF_AB);
    int*   flags  = (int*)(ws + OFF_FLAG);
    f16*   featT  = (f16*)(ws + OFF_FEATT);
    bool bigws = ws_size >= (size_t)NEED_A;

    front_kernel<<<dim3(2048), dim3(256), 0, stream>>>(
        fv, x_idx, maskp, mwords, flags, xstride, mstride, feat,
        attn_w, cls_w, cls_b, reg_w, reg_b, attn_b, awT, wcT, biasc, abf32);

    // GEMM1: logits = feat @ attn_w  (M=32000, N=1024 padded, K=768), BK=64, LDS-staged
    gemm_kernel<OUT_F16, false, false, 128, 256, 64, 2, false, 1><<<dim3(1024), dim3(256), 0, stream>>>(
        feat, nullptr, 768, awT, 768, logits, 1024, 32000, 1024, 768, 0, 0, 0,
        nullptr, nullptr, flags);
    // transpose feat->featT + softmax-scatter in one dispatch
    post_kernel<<<dim3(24576 + 32000), dim3(256), 0, stream>>>(
        logits, abf32, feat, bigws ? featT : nullptr);
    // GEMM2 (batched): att_feat = S @ feat  (M=1000, N=768, K=1024 padded, 32 batches)
    // BK=64 LDS-staged, batch->XCD swizzle, NT=2 persistence
    if (bigws) {
        gemm_kernel<OUT_F16, false, false, 128, 256, 64, 3, false, 2><<<dim3(512), dim3(256), 0, stream>>>(
            logits, nullptr, 1024, featT, 1024, attf, 768, 1000, 768, 1024,
            1024000L, 786432L, 768000L, nullptr, nullptr, flags);
    } else {
        gemm_kernel<OUT_F16, false, true, 128, 128, 32, 0, false, 1><<<dim3(6, 8, 32), dim3(256), 0, stream>>>(
            logits, nullptr, 1024, feat, 768, attf, 768, 1000, 768, 1000,
            1024000L, 768000L, 768000L, nullptr, nullptr, flags);
    }
    // GEMM3: out = [att_feat | feat] @ Wc, fused epilogue; BG path (B=wcT, TN=128 narrow),
    // A-only LDS (16 KB), BK=128
    gemm_kernel<OUT_FINAL, true, false, 64, 128, 128, 0, true, 1><<<dim3(1, 500, 1), dim3(256), 0, stream>>>(
        attf, feat, 768, wcT, 1536, d_out, 77, 32000, 75, 1536, 0, 0, 0,
        biasc, anchors, flags);
}